// Round 3
// baseline (157.210 us; speedup 1.0000x reference)
//
#include <hip/hip_runtime.h>
#include <hip/hip_bf16.h>
#include <stdint.h>

using bf16 = __hip_bfloat16;
typedef __attribute__((ext_vector_type(8))) __bf16 bf16x8;
typedef __attribute__((ext_vector_type(4))) float f32x4;

static __device__ __forceinline__ bf16 f2b(float x) { return __float2bfloat16(x); }
static __device__ __forceinline__ uint32_t pack2(float a, float b) {
    bf16 ha = f2b(a), hb = f2b(b);
    return (uint32_t)(*(const uint16_t*)&ha) | ((uint32_t)(*(const uint16_t*)&hb) << 16);
}

// =====================================================================
// Dispatch 1 (prep_mix): ALL pre-GEMM work in one launch.
//  [0,nbWc)      Wc = Wo @ Wv : 64x64 tile, BK=64. A staged from fp32 Wo
//                (float4 x2 -> pack -> swizzled ds_write_b128). B staged
//                from fp32 Wv via two-stage LDS transpose:
//                  stage1: Wv[k0+r][bn+c] -> bf16 Ts[r][c] (stride 68,
//                          b64 writes, conflict-free)
//                  stage2: gather 8 k's per (j,kb) from Ts columns (2-way
//                          free u16 reads) -> swizzled Bs row j, slot
//                          kb^(j&7)  (matches the MFMA reader's XOR).
//  [+nbWv)       Wv fp32->bf16 cast (8/thread)  -> Wv_b
//  [+nbVal)      value fp32->bf16 cast          -> value_b
//  [+nbBc)       bc[i] = Wo[i,:].bv + bo[i]  (4 rows/block, 1 row/wave)
// =====================================================================
__global__ __launch_bounds__(256, 4) void prep_mix_kernel(
    const float* __restrict__ value, const float* __restrict__ Wv,
    const float* __restrict__ Wo, const float* __restrict__ bv,
    const float* __restrict__ bo,
    bf16* __restrict__ value_b, bf16* __restrict__ Wv_b,
    bf16* __restrict__ Wc_b, float* __restrict__ bc,
    int nbWc, int nbWv, int nbVal, int dm)
{
    __shared__ bf16 As[64 * 64];   // 8 KB
    __shared__ bf16 Bs[64 * 64];   // 8 KB
    __shared__ bf16 Ts[64 * 68];   // 8.5 KB padded k-major staging

    const int blk = blockIdx.x;
    const int tid = threadIdx.x;

    if (blk < nbWc) {
        const int K = dm, N = dm;
        const int tpr = dm / 64;
        const int bm = (blk / tpr) * 64, bn = (blk % tpr) * 64;
        const int lane = tid & 63;
        const int wave = tid >> 6;
        const int wm = (wave >> 1) * 32;
        const int wn = (wave & 1) * 32;

        f32x4 acc[2][2] = {};

        // A staging from fp32 Wo (2 slots/thread: tid, tid+256)
        const int sa0 = tid, sa1 = tid + 256;
        const int ra0 = sa0 >> 3, pa0 = (sa0 & 7) ^ (ra0 & 7);
        const int ra1 = sa1 >> 3, pa1 = (sa1 & 7) ^ (ra1 & 7);
        const float* gA0 = Wo + (size_t)(bm + ra0) * K + pa0 * 8;
        const float* gA1 = Wo + (size_t)(bm + ra1) * K + pa1 * 8;

        // B stage1 coords: 16 float4 per Wv row, 16 rows per pass
        const int tx = tid & 15, ty = tid >> 4;

        const int fr = lane & 15;
        const int fkc = lane >> 4;
        const int xb = fr & 7;

        for (int k0 = 0; k0 < K; k0 += 64) {
            // ---- A: Wo fp32 -> bf16 -> swizzled As
            const float4 a0 = *(const float4*)(gA0 + k0);
            const float4 a1 = *(const float4*)(gA0 + k0 + 4);
            const float4 a2 = *(const float4*)(gA1 + k0);
            const float4 a3 = *(const float4*)(gA1 + k0 + 4);
            uint4 u0 = { pack2(a0.x, a0.y), pack2(a0.z, a0.w),
                         pack2(a1.x, a1.y), pack2(a1.z, a1.w) };
            uint4 u1 = { pack2(a2.x, a2.y), pack2(a2.z, a2.w),
                         pack2(a3.x, a3.y), pack2(a3.z, a3.w) };
            *(uint4*)(As + sa0 * 8) = u0;
            *(uint4*)(As + sa1 * 8) = u1;

            // ---- B stage1: Wv rows (k-major) -> bf16 Ts[r][c], stride 68
            #pragma unroll
            for (int p = 0; p < 4; ++p) {
                const int r = ty + p * 16;
                const float4 w = *(const float4*)(Wv + (size_t)(k0 + r) * dm + bn + tx * 4);
                uint2 t2;
                t2.x = pack2(w.x, w.y);
                t2.y = pack2(w.z, w.w);
                *(uint2*)((uint16_t*)Ts + r * 68 + tx * 4) = t2;
            }
            __syncthreads();

            // ---- B stage2: transpose Ts -> swizzled Bs (row j, k-contig)
            #pragma unroll
            for (int m = 0; m < 2; ++m) {
                const int s = 2 * tid + m;
                const int j = s >> 3, kb = s & 7;
                const uint16_t* tp = (const uint16_t*)Ts + kb * 8 * 68 + j;
                uint4 u;
                u.x = (uint32_t)tp[0]      | ((uint32_t)tp[68]     << 16);
                u.y = (uint32_t)tp[2 * 68] | ((uint32_t)tp[3 * 68] << 16);
                u.z = (uint32_t)tp[4 * 68] | ((uint32_t)tp[5 * 68] << 16);
                u.w = (uint32_t)tp[6 * 68] | ((uint32_t)tp[7 * 68] << 16);
                *(uint4*)(Bs + j * 64 + ((kb ^ (j & 7)) * 8)) = u;
            }
            __syncthreads();

            // ---- MFMA
            #pragma unroll
            for (int kk = 0; kk < 2; ++kk) {
                const int xsw = ((kk * 4 + fkc) ^ xb) * 8;
                bf16x8 af[2], bg[2];
                #pragma unroll
                for (int u = 0; u < 2; ++u) {
                    af[u] = *(const bf16x8*)(As + (wm + u * 16 + fr) * 64 + xsw);
                    bg[u] = *(const bf16x8*)(Bs + (wn + u * 16 + fr) * 64 + xsw);
                }
                #pragma unroll
                for (int i = 0; i < 2; ++i)
                    #pragma unroll
                    for (int j = 0; j < 2; ++j)
                        acc[i][j] = __builtin_amdgcn_mfma_f32_16x16x32_bf16(
                            af[i], bg[j], acc[i][j], 0, 0, 0);
            }
            __syncthreads();
        }

        const int quad = lane >> 4;
        #pragma unroll
        for (int j = 0; j < 2; ++j) {
            const int col = bn + wn + j * 16 + fr;
            #pragma unroll
            for (int i = 0; i < 2; ++i) {
                const int row0 = bm + wm + i * 16 + quad * 4;
                #pragma unroll
                for (int r = 0; r < 4; ++r)
                    Wc_b[(size_t)(row0 + r) * N + col] = f2b(acc[i][j][r]);
            }
        }
    } else if (blk < nbWc + nbWv) {
        const size_t i = ((size_t)(blk - nbWc) * 256 + tid) * 8;
        const float4 v0 = *(const float4*)(Wv + i);
        const float4 v1 = *(const float4*)(Wv + i + 4);
        uint4 u = { pack2(v0.x, v0.y), pack2(v0.z, v0.w),
                    pack2(v1.x, v1.y), pack2(v1.z, v1.w) };
        *(uint4*)(Wv_b + i) = u;
    } else if (blk < nbWc + nbWv + nbVal) {
        const size_t i = ((size_t)(blk - nbWc - nbWv) * 256 + tid) * 8;
        const float4 v0 = *(const float4*)(value + i);
        const float4 v1 = *(const float4*)(value + i + 4);
        uint4 u = { pack2(v0.x, v0.y), pack2(v0.z, v0.w),
                    pack2(v1.x, v1.y), pack2(v1.z, v1.w) };
        *(uint4*)(value_b + i) = u;
    } else {
        const int lane = tid & 63;
        const int wave = tid >> 6;
        const int row = (blk - nbWc - nbWv - nbVal) * 4 + wave;
        const float* wrow = Wo + (size_t)row * dm;
        float s = 0.f;
        for (int k = lane * 4; k < dm; k += 256) {
            const float4 w = *(const float4*)(wrow + k);
            const float4 x = *(const float4*)(bv + k);
            s += w.x * x.x + w.y * x.y + w.z * x.z + w.w * x.w;
        }
        #pragma unroll
        for (int off = 32; off >= 1; off >>= 1) s += __shfl_down(s, off, 64);
        if (lane == 0) bc[row] = s + bo[row];
    }
}

// =====================================================================
// Dispatch 2: big fused GEMM, BK=64. C = value_b @ Bcat^T,
// Bcat=[Wv_b;Wc_b]. bn<dm -> out1&out2 (+bv); bn>=dm -> out0 (+bc).
// Swizzle: slot s (r=s>>3) holds part (s&7)^(r&7); reader
// q=((kk*4+fkc)^(fr&7)) -> conflict-free. Epilogue: 17 KB Es ALIASED onto
// As|Bs (safe after the loop's final barrier) -> 32 KB LDS total.
// Output stores are nontemporal (48 MB write-once; keep L2 for operands);
// NT via ext-vector f32x4 (clang requires vector-of-float, not float4).
// =====================================================================
#define TM 128
#define TN 128
#define BK 64

__global__ __launch_bounds__(256, 2) void gemm_fused(
    const bf16* __restrict__ A, const bf16* __restrict__ Bcat,
    const float* __restrict__ bv, const float* __restrict__ bc,
    float* __restrict__ out0, float* __restrict__ out1, float* __restrict__ out2,
    int M, int dm)
{
    __shared__ __align__(16) char smem[(TM + TN) * BK * 2];  // 32 KB
    bf16* const As = (bf16*)smem;
    bf16* const Bs = (bf16*)smem + TM * BK;

    const int K = dm;
    const int tid = threadIdx.x;
    const int lane = tid & 63;
    const int wave = tid >> 6;
    const int wm = (wave >> 1) * 64;
    const int wn = (wave & 1) * 64;
    const int bm = blockIdx.x * TM;
    const int bn = blockIdx.y * TN;

    f32x4 acc[4][4] = {};

    // 4 slots per wave per matrix (1024 slots of 16 B per 16 KB tile)
    const bf16* gA[4]; const bf16* gB[4];
    bf16* lA[4]; bf16* lB[4];
    #pragma unroll
    for (int q = 0; q < 4; ++q) {
        const int s = wave * 256 + q * 64 + lane;
        const int r = s >> 3;
        const int p = (s & 7) ^ (r & 7);
        gA[q] = A + (size_t)(bm + r) * K + p * 8;
        gB[q] = Bcat + (size_t)(bn + r) * K + p * 8;
        lA[q] = As + s * 8;
        lB[q] = Bs + s * 8;
    }

    const int fr = lane & 15;
    const int fkc = lane >> 4;
    const int xb = fr & 7;

    for (int k0 = 0; k0 < K; k0 += BK) {
        #pragma unroll
        for (int q = 0; q < 4; ++q)
            __builtin_amdgcn_global_load_lds(
                (const __attribute__((address_space(1))) void*)(gA[q] + k0),
                (__attribute__((address_space(3))) void*)lA[q], 16, 0, 0);
        #pragma unroll
        for (int q = 0; q < 4; ++q)
            __builtin_amdgcn_global_load_lds(
                (const __attribute__((address_space(1))) void*)(gB[q] + k0),
                (__attribute__((address_space(3))) void*)lB[q], 16, 0, 0);
        __syncthreads();

        #pragma unroll
        for (int kk = 0; kk < 2; ++kk) {
            const int xsw = ((kk * 4 + fkc) ^ xb) * 8;
            bf16x8 af[4], bg[4];
            #pragma unroll
            for (int t = 0; t < 4; ++t) {
                af[t] = *(const bf16x8*)(As + (wm + t * 16 + fr) * BK + xsw);
                bg[t] = *(const bf16x8*)(Bs + (wn + t * 16 + fr) * BK + xsw);
            }
            #pragma unroll
            for (int i = 0; i < 4; ++i)
                #pragma unroll
                for (int j = 0; j < 4; ++j)
                    acc[i][j] = __builtin_amdgcn_mfma_f32_16x16x32_bf16(
                        af[i], bg[j], acc[i][j], 0, 0, 0);
        }
        __syncthreads();
    }

    const bool second = (bn >= dm);
    const int colbase = bn + wn - (second ? dm : 0);
    const float* bias = second ? bc : bv;
    float* o0 = second ? out0 : out1;
    float* o1 = second ? nullptr : out2;

    float bb[4];
    #pragma unroll
    for (int j = 0; j < 4; ++j) bb[j] = bias[colbase + j * 16 + fr];

    // epilogue staging reuses As|Bs (all LDS reads drained at final barrier)
    float* E = (float*)smem + wave * (16 * 68);
    const int quad = lane >> 4;
    const int cc = (lane & 15) * 4;

    #pragma unroll
    for (int i = 0; i < 4; ++i) {
        #pragma unroll
        for (int j = 0; j < 4; ++j)
            #pragma unroll
            for (int r = 0; r < 4; ++r)
                E[(quad * 4 + r) * 68 + j * 16 + fr] = acc[i][j][r] + bb[j];
        #pragma unroll
        for (int ph = 0; ph < 4; ++ph) {
            const int row = quad * 4 + ph;
            const f32x4 v = *(const f32x4*)(E + row * 68 + cc);
            const size_t gi = (size_t)(bm + wm + i * 16 + row) * dm + colbase + cc;
            __builtin_nontemporal_store(v, (f32x4*)(o0 + gi));
            if (o1) __builtin_nontemporal_store(v, (f32x4*)(o1 + gi));
        }
    }
}

// ---------------- fp32 fallback ----------------
__global__ __launch_bounds__(256) void gemm_f32_naive(
    const float* __restrict__ A, const float* __restrict__ B,
    const float* __restrict__ bias,
    float* __restrict__ C0, float* __restrict__ C1,
    int M, int N, int K)
{
    const size_t idx = (size_t)blockIdx.x * 256 + threadIdx.x;
    if (idx >= (size_t)M * N) return;
    const int row = (int)(idx / N), col = (int)(idx % N);
    const float* a = A + (size_t)row * K;
    const float* b = B + (size_t)col * K;
    float s = bias ? bias[col] : 0.0f;
    for (int k = 0; k < K; ++k) s += a[k] * b[k];
    C0[idx] = s;
    if (C1) C1[idx] = s;
}

// Math: softmax row-sums == 1 => out1 = out2 = value@Wv^T+bv,
// out0 = value@(Wo@Wv)^T + (Wo@bv+bo).
// Pipeline (2 dispatches): (1) prep_mix: Wc-GEMM (fp32 A from Wo, fp32 B
// from Wv via in-LDS transpose) + value/Wv casts + bc; (2) one
// 4096x2048x1024 bf16 GEMM, BK=64, NT output stores.
extern "C" void kernel_launch(void* const* d_in, const int* in_sizes, int n_in,
                              void* d_out, int out_size, void* d_ws, size_t ws_size,
                              hipStream_t stream)
{
    const float* value = (const float*)d_in[2];
    const float* Wv    = (const float*)d_in[7];
    const float* bv    = (const float*)d_in[8];
    const float* Wo    = (const float*)d_in[9];
    const float* bo    = (const float*)d_in[10];

    const int dm = in_sizes[8];
    const int M  = in_sizes[2] / dm;
    const size_t MN = (size_t)M * dm;

    float* out0 = (float*)d_out;
    float* out1 = out0 + MN;
    float* out2 = out1 + MN;

    const size_t dm2 = (size_t)dm * dm;
    // ws: value_b | Wv_b | Wc_b (contig pair = Bcat) | bc
    const size_t need = MN * 2 + dm2 * 2 * 2 + (size_t)dm * 4;
    const bool ok = (ws_size >= need) && (M % TM == 0) && (dm % TM == 0) &&
                    (MN % 2048 == 0) && (dm2 % 2048 == 0) && (dm % 64 == 0);
    if (ok) {
        char* ws = (char*)d_ws;
        bf16* value_b = (bf16*)ws;   ws += MN * 2;
        bf16* Wv_b    = (bf16*)ws;   ws += dm2 * 2;
        bf16* Wc_b    = (bf16*)ws;   ws += dm2 * 2;
        float* bc     = (float*)ws;

        const int nbWc  = (dm / 64) * (dm / 64);
        const int nbWv  = (int)(dm2 / 2048);
        const int nbVal = (int)(MN / 2048);
        const int nbBc  = dm / 4;
        prep_mix_kernel<<<nbWc + nbWv + nbVal + nbBc, 256, 0, stream>>>(
            value, Wv, Wo, bv, bo, value_b, Wv_b, Wc_b, bc,
            nbWc, nbWv, nbVal, dm);

        dim3 grid(M / TM, 2 * dm / TN);
        gemm_fused<<<grid, 256, 0, stream>>>(value_b, Wv_b, bv, bc,
                                             out0, out1, out2, M, dm);
    } else {
        const int nblk = (int)((MN + 255) / 256);
        gemm_f32_naive<<<nblk, 256, 0, stream>>>(value, Wv, bv, out1, out2, M, dm, dm);
        gemm_f32_naive<<<nblk, 256, 0, stream>>>(out1, Wo, bo, out0, nullptr, M, dm, dm);
    }
}